// Round 1
// 602.511 us; speedup vs baseline: 1.0200x; 1.0200x over previous
//
#include <hip/hip_runtime.h>
#include <math.h>

#pragma STDC FP_CONTRACT OFF

#define N 6000
#define NPAD 6144
#define C 81
#define PADDING 300
#define NMS_THRESH 0.5f
#define MASK_ELEMS (14 * 14 * 81) /* 15876 */
#define MASK_W 96                 /* u64 words per mask row (94 used, 96 for 16B align) */
#define NCHUNK 8
#define CHUNK 750                 /* 6000 / 8 */

typedef unsigned long long u64;

// ---------------------------------------------------------------------------
// Kernel 1: per-proposal decode. One WAVE per proposal (coalesced score
// reads), shuffle-tree argmax with exact first-occurrence semantics
// (strict >, tie -> lower index), lane 0 does the original box math verbatim.
// key = orderable(max_score) << 32 | ~i  -> u64 compare == (score desc, idx asc)
// ---------------------------------------------------------------------------
__global__ void decode_kernel(const float* __restrict__ meta,
                              const float* __restrict__ deltas,
                              const float* __restrict__ proposals,
                              const float* __restrict__ scores,
                              float* __restrict__ pbox,
                              float* __restrict__ area,
                              u64* __restrict__ skey) {
    int n = blockIdx.x * 4 + (threadIdx.x >> 6);
    int lane = threadIdx.x & 63;
    if (n >= N) return;

    const float* sr = scores + n * C;
    // lane covers class c = lane; 17 lanes also cover c = lane + 64.
    float s0 = sr[lane];
    float s1 = (lane < C - 64) ? sr[lane + 64] : -INFINITY;

    // local argmax candidate (value, index), first-occurrence: strict > only
    float av = s0;
    int ai = lane;
    if (s1 > av) { av = s1; ai = lane + 64; }
    // max over classes 1..C-1 (exclude class 0 == lane 0's s0)
    float mv = (lane >= 1) ? s0 : -INFINITY;
    mv = fmaxf(mv, s1);

    // wave reduce to lane 0 (self-combine for lanes near top is idempotent)
    for (int off = 32; off >= 1; off >>= 1) {
        float ov = __shfl_down(av, off);
        int oi = __shfl_down(ai, off);
        float om = __shfl_down(mv, off);
        if (ov > av || (ov == av && oi < ai)) { av = ov; ai = oi; }
        mv = fmaxf(mv, om);
    }

    if (lane == 0) {
        int top = ai;
        float ms = mv;

        float Hm = meta[0], Wm = meta[1], scale = meta[2];
        float b0 = proposals[n * 4 + 0] / scale;
        float b1 = proposals[n * 4 + 1] / scale;
        float b2 = proposals[n * 4 + 2] / scale;
        float b3 = proposals[n * 4 + 3] / scale;
        float w = b2 - b0 + 1.0f;
        float h = b3 - b1 + 1.0f;
        float cx = b0 + 0.5f * w;
        float cy = b1 + 0.5f * h;

        const float* dr = deltas + n * (4 * C) + 4 * top;
        float dx = dr[0], dy = dr[1], dw = dr[2], dh = dr[3];
        float pcx = dx * w + cx;
        float pcy = dy * h + cy;
        float pw = expf(dw) * w;
        float ph = expf(dh) * h;
        float x1 = pcx - 0.5f * pw;
        float y1 = pcy - 0.5f * ph;
        float x2 = pcx + 0.5f * pw;
        float y2 = pcy + 0.5f * ph;
        x1 = fminf(fmaxf(x1, 0.0f), Wm - 1.0f);
        y1 = fminf(fmaxf(y1, 0.0f), Hm - 1.0f);
        x2 = fminf(fmaxf(x2, 0.0f), Wm - 1.0f);
        y2 = fminf(fmaxf(y2, 0.0f), Hm - 1.0f);

        pbox[n * 4 + 0] = x1;
        pbox[n * 4 + 1] = y1;
        pbox[n * 4 + 2] = x2;
        pbox[n * 4 + 3] = y2;
        area[n] = (x2 - x1 + 1.0f) * (y2 - y1 + 1.0f);

        unsigned int b = __float_as_uint(ms);
        unsigned int u = b ^ ((b & 0x80000000u) ? 0xFFFFFFFFu : 0x80000000u);
        skey[n] = ((u64)u << 32) | (unsigned int)(~n);
    }
}

// ---------------------------------------------------------------------------
// Kernel 2: brute-force rank (partial counts per key-chunk; no atomics).
// ---------------------------------------------------------------------------
__global__ void rank_kernel(const u64* __restrict__ skey,
                            int* __restrict__ rank_part) {
    __shared__ u64 lk[CHUNK];
    int chunk = blockIdx.y;
    int t = threadIdx.x;
    int j0 = chunk * CHUNK;
    for (int j = t; j < CHUNK; j += 256) lk[j] = skey[j0 + j];
    __syncthreads();

    int i = blockIdx.x * 256 + t;
    if (i >= N) return;
    u64 mykey = skey[i];
    int cnt = 0;
    for (int j = 0; j < CHUNK; ++j) cnt += (lk[j] > mykey) ? 1 : 0;
    rank_part[chunk * NPAD + i] = cnt;
}

// ---------------------------------------------------------------------------
// Kernel 3: scatter into sorted order (SoA box arrays for the IoU kernel).
// ---------------------------------------------------------------------------
__global__ void scatter_kernel(const int* __restrict__ rank_part,
                               const float* __restrict__ pbox,
                               const float* __restrict__ area,
                               int* __restrict__ sidx,
                               float* __restrict__ sx1, float* __restrict__ sy1,
                               float* __restrict__ sx2, float* __restrict__ sy2,
                               float* __restrict__ sarea) {
    int i = blockIdx.x * blockDim.x + threadIdx.x;
    if (i >= N) return;
    int r = 0;
    for (int c = 0; c < NCHUNK; ++c) r += rank_part[c * NPAD + i];
    sidx[r] = i;
    sx1[r] = pbox[i * 4 + 0];
    sy1[r] = pbox[i * 4 + 1];
    sx2[r] = pbox[i * 4 + 2];
    sy2[r] = pbox[i * 4 + 3];
    sarea[r] = area[i];
}

// ---------------------------------------------------------------------------
// Kernel 4: suppression bitmask matrix — UPPER TRIANGLE ONLY.
// Scan invariant: p is always the FIRST zero bit, so all bits < p are 1
// when row p is OR'd; words < (p>>6) may hold garbage (never written) and
// OR-ing them is provably harmless. Start each row at word p>>6.
// ---------------------------------------------------------------------------
__global__ void __launch_bounds__(256) iou_kernel(const float* __restrict__ sx1,
                                                  const float* __restrict__ sy1,
                                                  const float* __restrict__ sx2,
                                                  const float* __restrict__ sy2,
                                                  const float* __restrict__ sarea,
                                                  u64* __restrict__ mask) {
    int p = blockIdx.x * 4 + (threadIdx.x >> 6);
    int lane = threadIdx.x & 63;
    if (p >= N) return;

    float wx1 = sx1[p], wy1 = sy1[p], wx2 = sx2[p], wy2 = sy2[p];
    float war = sarea[p];
    u64* row = mask + (size_t)p * MASK_W;

    for (int w = (p >> 6); w < 94; ++w) {
        int q = w * 64 + lane;  // < 6144, arrays padded
        float xx1 = fmaxf(wx1, sx1[q]);
        float yy1 = fmaxf(wy1, sy1[q]);
        float xx2 = fminf(wx2, sx2[q]);
        float yy2 = fminf(wy2, sy2[q]);
        float inter = fmaxf(xx2 - xx1 + 1.0f, 0.0f) * fmaxf(yy2 - yy1 + 1.0f, 0.0f);
        float iou = inter / (war + sarea[q] - inter);
        u64 bal = __ballot(iou > NMS_THRESH);
        if (lane == 0) row[w] = bal;
    }
}

// ---------------------------------------------------------------------------
// Kernel 5: serial scan — single wave, suppressed-mask in registers.
// A/B ping-pong 16-row register pipeline: when p crosses into B, swap roles
// and immediately ISSUE the next 8-row prefetch; those loads complete while
// the next ~8 kept steps process the swapped-in rows (no vmcnt(0) stall on
// the dense-kept path). p extraction uses scalar readlane (no ds_bpermute).
// Writes sorted POSITION p; gather does the sidx indirection.
// ---------------------------------------------------------------------------
__device__ __forceinline__ void load_rows8(const u64* __restrict__ mask,
                                           int rowbase, int lane,
                                           u64* bx, u64* by) {
    if (lane < 48) {
#pragma unroll
        for (int k = 0; k < 8; ++k) {
            int r = rowbase + k;
            r = (r < N) ? r : (N - 1);
            const u64* q = mask + (size_t)r * MASK_W + 2 * lane;
            bx[k] = q[0];
            by[k] = q[1];
        }
    }
}

__global__ void scan_kernel(const u64* __restrict__ mask,
                            int* __restrict__ out_pos,
                            float* __restrict__ out_valid) {
    int lane = threadIdx.x;
    int w0 = 2 * lane, w1 = 2 * lane + 1;

    u64 m_lo = (w0 < 93) ? 0ULL : (w0 == 93 ? 0xFFFF000000000000ULL : ~0ULL);
    u64 m_hi = (w1 < 93) ? 0ULL : (w1 == 93 ? 0xFFFF000000000000ULL : ~0ULL);

    u64 ax[8], ay[8], bx[8], by[8];
#pragma unroll
    for (int k = 0; k < 8; ++k) { ax[k] = 0; ay[k] = 0; bx[k] = 0; by[k] = 0; }

    // First p is always 0 (no bits set below padding) — preload [0,16).
    int base = 0;
    load_rows8(mask, 0, lane, ax, ay);
    load_rows8(mask, 8, lane, bx, by);

    int r = 0;
    while (r < PADDING) {
        u64 z0 = ~m_lo, z1 = ~m_hi;
        u64 bal = __ballot((z0 | z1) != 0ULL);
        if (bal == 0ULL) break;
        int lsrc = (int)__ffsll(bal) - 1;
        int local = (z0 != 0ULL) ? ((int)__ffsll(z0) - 1) : (64 + (int)__ffsll(z1) - 1);
        int p = __builtin_amdgcn_readlane(lane * 128 + local, lsrc);

        if (p >= base + 16) {
            // rare big jump: cold reload both windows
            base = p;
            load_rows8(mask, base, lane, ax, ay);
            load_rows8(mask, base + 8, lane, bx, by);
        } else if (p >= base + 8) {
            // swap B -> A (loads long since landed), prefetch next 8 rows
            base += 8;
#pragma unroll
            for (int k = 0; k < 8; ++k) { ax[k] = bx[k]; ay[k] = by[k]; }
            load_rows8(mask, base + 8, lane, bx, by);
        }
        int s = p - base;  // in [0,8)
        u64 vx = ax[0], vy = ay[0];
#pragma unroll
        for (int k = 1; k < 8; ++k) {
            if (s == k) { vx = ax[k]; vy = ay[k]; }
        }
        if (lane < 48) { m_lo |= vx; m_hi |= vy; }
        if (lane == 0) { out_pos[r] = p; out_valid[r] = 1.0f; }
        ++r;
    }
    for (; r < PADDING; ++r) {
        if (lane == 0) { out_pos[r] = 0; out_valid[r] = 0.0f; }
    }
}

// ---------------------------------------------------------------------------
// Kernel 6: gather outputs. One block per selected row.
// out layout: boxes [300*4] | scores [300*81] | masks [300*15876]
// ---------------------------------------------------------------------------
__global__ void gather_kernel(const float* __restrict__ pbox,
                              const float* __restrict__ scores,
                              const float* __restrict__ masks,
                              const int* __restrict__ sidx,
                              const int* __restrict__ out_pos,
                              const float* __restrict__ valid,
                              float* __restrict__ out) {
    int b = blockIdx.x;  // 0..PADDING-1
    int tid = threadIdx.x;
    int i = sidx[out_pos[b]];
    float vf = valid[b];

    if (tid < 4) out[b * 4 + tid] = pbox[i * 4 + tid] * vf;
    if (tid < C) out[PADDING * 4 + b * C + tid] = scores[i * C + tid] * vf;

    const float4* src = (const float4*)(masks + (size_t)i * MASK_ELEMS);
    float4* dst = (float4*)(out + PADDING * 4 + PADDING * C + (size_t)b * MASK_ELEMS);
    for (int m = tid; m < MASK_ELEMS / 4; m += 256) {
        float4 v = src[m];
        dst[m] = make_float4(v.x * vf, v.y * vf, v.z * vf, v.w * vf);
    }
}

extern "C" void kernel_launch(void* const* d_in, const int* in_sizes, int n_in,
                              void* d_out, int out_size, void* d_ws, size_t ws_size,
                              hipStream_t stream) {
    const float* meta      = (const float*)d_in[0];
    const float* deltas    = (const float*)d_in[1];
    const float* proposals = (const float*)d_in[2];
    const float* scores    = (const float*)d_in[3];
    const float* masks     = (const float*)d_in[4];
    float* out = (float*)d_out;

    // Workspace layout (bytes). Total ~5.13 MB.
    char* ws = (char*)d_ws;
    u64*   mask      = (u64*)(ws);                       // 6000*96*8 = 4,608,000
    u64*   skey      = (u64*)(ws + 4608000);             // 6144*8    =    49,152
    float* pbox      = (float*)(ws + 4657152);           // 6000*4*4  =    96,000
    float* area      = (float*)(ws + 4753152);           // 6000*4    =    24,000
    int*   rank_part = (int*)(ws + 4777152);             // 8*6144*4  =   196,608
    int*   sidx      = (int*)(ws + 4973760);             // 6144*4    =    24,576
    float* sx1       = (float*)(ws + 4998336);           // 6144*4 each
    float* sy1       = (float*)(ws + 5022912);
    float* sx2       = (float*)(ws + 5047488);
    float* sy2       = (float*)(ws + 5072064);
    float* sarea     = (float*)(ws + 5096640);
    int*   out_pos   = (int*)(ws + 5121216);             // 300*4
    float* out_valid = (float*)(ws + 5122416);           // 300*4

    decode_kernel<<<1500, 256, 0, stream>>>(meta, deltas, proposals, scores, pbox, area, skey);
    rank_kernel<<<dim3(24, NCHUNK), 256, 0, stream>>>(skey, rank_part);
    scatter_kernel<<<24, 256, 0, stream>>>(rank_part, pbox, area, sidx, sx1, sy1, sx2, sy2, sarea);
    iou_kernel<<<1500, 256, 0, stream>>>(sx1, sy1, sx2, sy2, sarea, mask);
    scan_kernel<<<1, 64, 0, stream>>>(mask, out_pos, out_valid);
    gather_kernel<<<PADDING, 256, 0, stream>>>(pbox, scores, masks, sidx, out_pos, out_valid, out);
}